// Round 7
// baseline (104.361 us; speedup 1.0000x reference)
//
#include <hip/hip_runtime.h>

// FWHT 4096, natural (Sylvester) order. v6: v1's proven structure (3x wht16 in
// regs + 2 padded-LDS exchanges + stride-256 coalesced scalar stores), with a
// 2-row software pipeline per block: both rows' loads are issued up front so
// row B's HBM latency hides under row A's compute+LDS+barrier phase.
// v1=97.3us, v3(3rd xchg+vec stores)=111.8, v5(1 barrier,DPP/swizzle)=101.2
// -> LDS micro-structure is not the limiter; loads-in-flight is the last lever.

typedef float f32x4 __attribute__((ext_vector_type(4)));

__device__ __forceinline__ void wht16(float v[16]) {
#pragma unroll
    for (int h = 1; h < 16; h <<= 1) {
#pragma unroll
        for (int i = 0; i < 16; i++) {
            if ((i & h) == 0) {
                float a = v[i], b = v[i ^ h];
                v[i]     = a + b;
                v[i ^ h] = a - b;
            }
        }
    }
}

__device__ __forceinline__ void process_row(float v[16], float* lds, int t,
                                            float* __restrict__ outrow) {
    const int u_hi = t >> 4;
    const int u_lo = t & 15;

    // phase 1: bits 0-3 in regs
    wht16(v);

    // exchange 1: thread t=(b2,b1) regs=b0 -> thread (b2,b0) regs=b1
#pragma unroll
    for (int r = 0; r < 16; r++) lds[t * 17 + r] = v[r];
    __syncthreads();
#pragma unroll
    for (int k = 0; k < 16; k++) v[k] = lds[(u_hi * 16 + k) * 17 + u_lo];

    // phase 2: bits 4-7
    wht16(v);

    // exchange 2: write back to the exact slots just read (race-free without a
    // pre-barrier), re-read along b2
#pragma unroll
    for (int k = 0; k < 16; k++) lds[(u_hi * 16 + k) * 17 + u_lo] = v[k];
    __syncthreads();
#pragma unroll
    for (int m = 0; m < 16; m++) v[m] = lds[(m * 16 + u_hi) * 17 + u_lo];

    // phase 3: bits 8-11
    wht16(v);

    // store: per m, wave writes 256B contiguous (fully line-coalesced)
#pragma unroll
    for (int m = 0; m < 16; m++) outrow[m * 256 + t] = v[m];
}

__global__ __launch_bounds__(256) void fwht4096x2_kernel(const float* __restrict__ in,
                                                         float* __restrict__ out) {
    __shared__ float lds[256 * 17];

    const int t = threadIdx.x;
    const size_t base = (size_t)blockIdx.x * 2 * 4096;

    const f32x4* pa = (const f32x4*)(in + base + t * 16);
    const f32x4* pb = (const f32x4*)(in + base + 4096 + t * 16);

    // ---- issue ALL 8 dwordx4 loads (rows A and B) before any compute ----
    f32x4 fa[4], fb[4];
#pragma unroll
    for (int q = 0; q < 4; q++) fa[q] = pa[q];
#pragma unroll
    for (int q = 0; q < 4; q++) fb[q] = pb[q];

    float v[16];

    // ---- row A ----
#pragma unroll
    for (int q = 0; q < 4; q++) {
        v[4 * q + 0] = fa[q].x; v[4 * q + 1] = fa[q].y;
        v[4 * q + 2] = fa[q].z; v[4 * q + 3] = fa[q].w;
    }
    process_row(v, lds, t, out + base);

    // protect LDS reuse: A's last reads must complete before B's first writes
    __syncthreads();

    // ---- row B (loads have been in flight through all of row A) ----
#pragma unroll
    for (int q = 0; q < 4; q++) {
        v[4 * q + 0] = fb[q].x; v[4 * q + 1] = fb[q].y;
        v[4 * q + 2] = fb[q].z; v[4 * q + 3] = fb[q].w;
    }
    process_row(v, lds, t, out + base + 4096);
}

extern "C" void kernel_launch(void* const* d_in, const int* in_sizes, int n_in,
                              void* d_out, int out_size, void* d_ws, size_t ws_size,
                              hipStream_t stream) {
    const float* x = (const float*)d_in[0];
    float* out     = (float*)d_out;
    const int rows = in_sizes[0] / 4096;   // 16384
    fwht4096x2_kernel<<<dim3(rows / 2), dim3(256), 0, stream>>>(x, out);
}

// Round 8
// 97.402 us; speedup vs baseline: 1.0715x; 1.0715x over previous
//
#include <hip/hip_runtime.h>

// FWHT, natural (Sylvester) order: out[c] = sum_j (-1)^popcount(c&j) x[j]
// D = 4096 = 16*16*16 -> three in-register W16 phases + two LDS digit swaps.
// FINAL (v1 reverted): best measured 97.3 us = 5.52 TB/s effective (88% of
// the 6.29 TB/s copy ceiling). Falsified alternatives on this structure:
//   v3: +3rd LDS exchange & dwordx4 stores      -> 111.8 us (LDS not hidden)
//   v2: nontemporal stores                      -> 371 us   (2.7x WRITE_SIZE
//       amplification on gfx950 nt path; FETCH halved but swamped)
//   v5: 1-barrier DPP/ds_swizzle/shfl variant   -> 101.2 us
//   v6: 2-row issue-early software pipeline     -> 104.4 us
// Scalar stride-256 stores are already fully line-coalesced per wave inst;
// the residual 12% vs copy is the mandatory load->transpose->store serial
// dependency (every output byte depends on the whole 16KB row).

__device__ __forceinline__ void wht16(float v[16]) {
#pragma unroll
    for (int h = 1; h < 16; h <<= 1) {
#pragma unroll
        for (int i = 0; i < 16; i++) {
            if ((i & h) == 0) {
                float a = v[i];
                float b = v[i ^ h];
                v[i]     = a + b;
                v[i ^ h] = a - b;
            }
        }
    }
}

__global__ __launch_bounds__(256) void fwht4096_kernel(const float* __restrict__ in,
                                                       float* __restrict__ out) {
    // padded LDS: logical j in [0,4096) stored at (j>>4)*17 + (j&15)
    __shared__ float lds[256 * 17];

    const int row = blockIdx.x;
    const int t   = threadIdx.x;

    const float* rp = in + (size_t)row * 4096;
    float v[16];

    // ---- load: thread t owns j = t*16 + r (contiguous 64B -> 4x float4) ----
    const float4* p4 = (const float4*)(rp + t * 16);
#pragma unroll
    for (int q = 0; q < 4; q++) {
        float4 f = p4[q];
        v[4 * q + 0] = f.x;
        v[4 * q + 1] = f.y;
        v[4 * q + 2] = f.z;
        v[4 * q + 3] = f.w;
    }

    // ---- phase 1: W16 over bits 0-3 ----
    wht16(v);

    // ---- exchange 1: j = t*16 + r  ->  thread holds varying bits 4-7 ----
#pragma unroll
    for (int r = 0; r < 16; r++) lds[t * 17 + r] = v[r];
    __syncthreads();

    const int u_hi = t >> 4;
    const int u_lo = t & 15;
#pragma unroll
    for (int k = 0; k < 16; k++) v[k] = lds[(u_hi * 16 + k) * 17 + u_lo];

    // ---- phase 2: W16 over bits 4-7 ----
    wht16(v);

    // ---- exchange 2: write back to the exact slots this thread read (no race,
    //      no sync needed before the write), then re-read along bits 8-11 ----
#pragma unroll
    for (int k = 0; k < 16; k++) lds[(u_hi * 16 + k) * 17 + u_lo] = v[k];
    __syncthreads();

#pragma unroll
    for (int m = 0; m < 16; m++) v[m] = lds[(m * 16 + u_hi) * 17 + u_lo];

    // ---- phase 3: W16 over bits 8-11 ----
    wht16(v);

    // ---- store: thread holds j = m*256 + t  -> per-m wave-contiguous 256B ----
    float* op = out + (size_t)row * 4096 + t;
#pragma unroll
    for (int m = 0; m < 16; m++) op[m * 256] = v[m];
}

extern "C" void kernel_launch(void* const* d_in, const int* in_sizes, int n_in,
                              void* d_out, int out_size, void* d_ws, size_t ws_size,
                              hipStream_t stream) {
    const float* x = (const float*)d_in[0];
    float* out     = (float*)d_out;
    const int rows = in_sizes[0] / 4096;   // 16384
    fwht4096_kernel<<<dim3(rows), dim3(256), 0, stream>>>(x, out);
}